// Round 10
// baseline (94.155 us; speedup 1.0000x reference)
//
#include <hip/hip_runtime.h>

typedef unsigned short u16;
typedef unsigned int   u32;
typedef __attribute__((ext_vector_type(8))) __bf16 bf16x8;
typedef __attribute__((ext_vector_type(4))) float  f32x4;
typedef __attribute__((ext_vector_type(4))) u16    u16x4;
typedef __attribute__((ext_vector_type(4))) u32    u32x4;

#define DEV __device__ __forceinline__

DEV u16 f2b(float f){ union{float f;u32 u;}a; a.f=f; u32 r=a.u + 0x7FFFu + ((a.u>>16)&1u); return (u16)(r>>16); }
DEV float b2f(u16 h){ union{u32 u;float f;}a; a.u=((u32)h)<<16; return a.f; }

typedef __attribute__((address_space(1))) void* gp1;
typedef __attribute__((address_space(3))) void* lp3;
DEV void gl16(const void* g, void* l){
  __builtin_amdgcn_global_load_lds((gp1)g, (lp3)l, 16, 0, 0);
}

struct GemmArgs {
  const u16* A; const u16* B; int K; int lda; int ldb;
  u16* outB; int ldB;
  u16* outBT;
  const u16* Yprev;
};

// ---------------------------------------------------------------------------
// L1 prep: transposes (blocks 0..703) + elementwise (rest)
// P: [x | u | w]; Rt: 256x640 = [C1 | D12]; Qt y-rows: [C2 | 0 | D21]
// McatT rows: [F^T | B2^T | B1^T]
// ---------------------------------------------------------------------------
__global__ __launch_bounds__(256) void k_prepc(
    const float* __restrict__ x,  const float* __restrict__ u,
    const float* __restrict__ C1, const float* __restrict__ D11,
    const float* __restrict__ D12, const float* __restrict__ Lam,
    const float* __restrict__ E,  const float* __restrict__ F,
    const float* __restrict__ B1, const float* __restrict__ B2,
    const float* __restrict__ C2, const float* __restrict__ D21,
    u16* Ebf, u16* Y0, u16* Z0, u16* McatT, u16* Qt, u16* Rt,
    float* invLam, u16* Ddg2, float* Dt16, u16* P)
{
  if (blockIdx.x < 704) {                   // tiled transposes
    __shared__ float t[32][33];
    int bid = blockIdx.x;
    const int tx = threadIdx.x & 31, ty = threadIdx.x >> 5;
    const float* src; u16* dst; int srcC, nA, task;
    if (bid < 256)      { task = 0; src = E;   srcC = 512; dst = Z0;    nA = 16; }
    else if (bid < 512) { task = 1; src = F;   srcC = 512; dst = McatT; nA = 16; bid -= 256; }
    else if (bid < 640) { task = 2; src = B1;  srcC = 256; dst = McatT + (size_t)640 * 512; nA = 8;  bid -= 512; }
    else                { task = 3; src = B2;  srcC = 128; dst = McatT + (size_t)512 * 512; nA = 4;  bid -= 640; }
    const int a0 = (bid % nA) * 32;
    const int b0 = (bid / nA) * 32;
    #pragma unroll
    for (int k = 0; k < 4; k++) {
      int srow = b0 + ty + 8 * k;
      t[ty + 8 * k][tx] = src[(size_t)srow * srcC + a0 + tx];
    }
    __syncthreads();
    #pragma unroll
    for (int k = 0; k < 4; k++) {
      int drow = a0 + ty + 8 * k, dcol = b0 + tx;
      float v = t[tx][ty + 8 * k];
      if (task == 0) v = ((drow == dcol) ? 2.f : 0.f) - v;
      dst[(size_t)drow * 512 + dcol] = f2b(v);
    }
    return;
  }
  int idx = (blockIdx.x - 704) * 256 + threadIdx.x;
  if (idx < 262144) {                       // Ebf, Y0 = 2I-E
    int i = idx >> 9, j = idx & 511;
    float e = E[idx];
    Ebf[idx] = f2b(e);
    float dij = (i == j) ? 2.f : 0.f;
    Y0[idx] = f2b(dij - e);
    return;
  }
  idx -= 262144;
  if (idx < 114688) {                       // Qt rows 512..639 (y part)
    int j = idx / 896, k = idx - j * 896;
    float v = (k < 512) ? C2[j * 512 + k]
              : (k < 640 ? 0.f : D21[j * 256 + (k - 640)]);
    Qt[(size_t)(512 + j) * 896 + k] = f2b(v);
    return;
  }
  idx -= 114688;
  if (idx < 163840) {                       // Rt (256x640): [C1 | D12]
    int n = idx / 640, k = idx - n * 640;
    float v = (k < 512) ? C1[n * 512 + k] : D12[n * 128 + (k - 512)];
    Rt[idx] = f2b(v);
    return;
  }
  idx -= 163840;
  if (idx < 256) { invLam[idx] = 1.f / Lam[idx * 257]; return; }
  idx -= 256;
  if (idx < 65536) {                        // Ddg2 fragment layout
    int sb = idx >> 13, t = (idx >> 9) & 15, l = (idx >> 3) & 63, j = idx & 7;
    int r = l & 15, g = l >> 4;
    int n = t * 16 + r, k = sb * 32 + g * 8 + j;
    Ddg2[idx] = f2b(D11[n * 256 + k] * (1.f / Lam[n * 257]));
    return;
  }
  idx -= 65536;
  if (idx < 4096) {                         // Dt16 triangular diag blocks
    int T = idx >> 8, k2 = (idx >> 4) & 15, n2 = idx & 15;
    float v = 0.f;
    if (n2 > k2) {
      int n = T * 16 + n2;
      v = D11[n * 256 + T * 16 + k2] * (1.f / Lam[n * 257]);
    }
    Dt16[idx] = v;
    return;
  }
  idx -= 4096;
  {                                         // P = [x | u | .] bf16
    int b = idx / 160, t = idx - b * 160;
    f32x4 s; u16* dst;
    if (t < 128) { s = *(const f32x4*)(x + (size_t)b * 512 + t * 4); dst = P + (size_t)b * 896 + t * 4; }
    else         { s = *(const f32x4*)(u + (size_t)b * 128 + (t - 128) * 4); dst = P + (size_t)b * 896 + 512 + (t - 128) * 4; }
    u16x4 o; o.x = f2b(s.x); o.y = f2b(s.y); o.z = f2b(s.z); o.w = f2b(s.w);
    *(u16x4*)dst = o;
  }
}

// ---------------------------------------------------------------------------
// 64x64-tile NT GEMM body, 256 threads (2x2 waves of 32x32)
// ---------------------------------------------------------------------------
template<int EPI>
DEV void gemm64_body(const GemmArgs& g, int bm, int bn, u16* As, u16* Bs)
{
  const int tid = threadIdx.x;
  const int l = tid & 63, w = tid >> 6;
  const int K = g.K;
  const size_t rowbA = (size_t)g.lda * 2, rowbB = (size_t)g.ldb * 2;
  const char* Ab = (const char*)g.A + (size_t)bm * 64 * rowbA;
  const char* Bb = (const char*)g.B + (size_t)bn * 64 * rowbB;
  const int o = tid * 16;
  const int r0 = o >> 6;
  const int cs = (((o >> 4) ^ r0) & 3) << 4;
  char* AsB = (char*)As; char* BsB = (char*)Bs;
  const int wm = w >> 1, wn = w & 1;
  const int lr = l & 15, lk = l >> 4;
  const int slot = ((lk ^ lr) & 3) << 4;

  f32x4 acc[2][2];
  const f32x4 zz = {0.f, 0.f, 0.f, 0.f};
  acc[0][0] = zz; acc[0][1] = zz; acc[1][0] = zz; acc[1][1] = zz;

  for (int k0 = 0; k0 < K; k0 += 32) {
    gl16(Ab + (size_t)r0 * rowbA + k0 * 2 + cs, AsB + o);
    gl16(Bb + (size_t)r0 * rowbB + k0 * 2 + cs, BsB + o);
    __syncthreads();
    bf16x8 af[2], bfv[2];
    #pragma unroll
    for (int mi = 0; mi < 2; mi++)
      af[mi] = *(const bf16x8*)(AsB + (wm * 32 + mi * 16 + lr) * 64 + slot);
    #pragma unroll
    for (int ni = 0; ni < 2; ni++)
      bfv[ni] = *(const bf16x8*)(BsB + (wn * 32 + ni * 16 + lr) * 64 + slot);
    #pragma unroll
    for (int mi = 0; mi < 2; mi++)
      #pragma unroll
      for (int ni = 0; ni < 2; ni++)
        acc[mi][ni] = __builtin_amdgcn_mfma_f32_16x16x32_bf16(af[mi], bfv[ni], acc[mi][ni], 0, 0, 0);
    __syncthreads();
  }

  #pragma unroll
  for (int mi = 0; mi < 2; mi++) {
    #pragma unroll
    for (int ni = 0; ni < 2; ni++) {
      const int row0 = bm * 64 + wm * 32 + mi * 16 + lk * 4;
      const int col  = bn * 64 + wn * 32 + ni * 16 + lr;
      if (EPI == 2) {
        #pragma unroll
        for (int r = 0; r < 4; r++)
          g.outB[(size_t)(row0 + r) * g.ldB + col] = f2b(acc[mi][ni][r]);
      } else if (EPI == 3) {
        #pragma unroll
        for (int r = 0; r < 4; r++)
          g.outBT[(size_t)col * 512 + (row0 + r)] = f2b(acc[mi][ni][r]);
      }
    }
  }
}

// ---------------------------------------------------------------------------
// 64x64-tile NT GEMM body, 128 threads (2 waves of 32x64); EPI 4 = Y1
// ---------------------------------------------------------------------------
template<int EPI>
DEV void gemm64h_body(const GemmArgs& g, int bm, int bn, u16* As, u16* Bs)
{
  const int tid = threadIdx.x;
  const int l = tid & 63, w = tid >> 6;           // w in {0,1}
  const int K = g.K;
  const size_t rowbA = (size_t)g.lda * 2, rowbB = (size_t)g.ldb * 2;
  const char* Ab = (const char*)g.A + (size_t)bm * 64 * rowbA;
  const char* Bb = (const char*)g.B + (size_t)bn * 64 * rowbB;
  const int o1 = tid * 16, o2 = o1 + 2048;
  const int rA1 = o1 >> 6, rA2 = o2 >> 6;
  const int cs1 = (((o1 >> 4) ^ rA1) & 3) << 4;
  const int cs2 = (((o2 >> 4) ^ rA2) & 3) << 4;
  char* AsB = (char*)As; char* BsB = (char*)Bs;
  const int lr = l & 15, lk = l >> 4;
  const int slot = ((lk ^ lr) & 3) << 4;

  f32x4 acc[2][4];
  const f32x4 zz = {0.f, 0.f, 0.f, 0.f};
  #pragma unroll
  for (int i = 0; i < 2; i++)
    #pragma unroll
    for (int j = 0; j < 4; j++) acc[i][j] = zz;

  for (int k0 = 0; k0 < K; k0 += 32) {
    gl16(Ab + (size_t)rA1 * rowbA + k0 * 2 + cs1, AsB + o1);
    gl16(Ab + (size_t)rA2 * rowbA + k0 * 2 + cs2, AsB + o2);
    gl16(Bb + (size_t)rA1 * rowbB + k0 * 2 + cs1, BsB + o1);
    gl16(Bb + (size_t)rA2 * rowbB + k0 * 2 + cs2, BsB + o2);
    __syncthreads();
    bf16x8 af[2], bfv[4];
    #pragma unroll
    for (int mi = 0; mi < 2; mi++)
      af[mi] = *(const bf16x8*)(AsB + (w * 32 + mi * 16 + lr) * 64 + slot);
    #pragma unroll
    for (int ni = 0; ni < 4; ni++)
      bfv[ni] = *(const bf16x8*)(BsB + (ni * 16 + lr) * 64 + slot);
    #pragma unroll
    for (int mi = 0; mi < 2; mi++)
      #pragma unroll
      for (int ni = 0; ni < 4; ni++)
        acc[mi][ni] = __builtin_amdgcn_mfma_f32_16x16x32_bf16(af[mi], bfv[ni], acc[mi][ni], 0, 0, 0);
    __syncthreads();
  }

  #pragma unroll
  for (int mi = 0; mi < 2; mi++) {
    #pragma unroll
    for (int ni = 0; ni < 4; ni++) {
      const int row0 = bm * 64 + w * 32 + mi * 16 + lk * 4;
      const int col  = bn * 64 + ni * 16 + lr;
      if (EPI == 4) {
        #pragma unroll
        for (int r = 0; r < 4; r++) {
          int row = row0 + r;
          float d = 2.f * b2f(g.Yprev[row * 512 + col]) - acc[mi][ni][r];
          g.outB[(size_t)row * 512 + col] = f2b(d);
        }
      }
    }
  }
}

// ---------------------------------------------------------------------------
// L2: blocks [0,256) = base2 GEMM (64x128, K=640, XCD-swizzled);
//     blocks [256,320) = T0T = (E@Y0)^T via gemm64_body<3>
// ---------------------------------------------------------------------------
__global__ __launch_bounds__(256) void gemm_b2(
    const u16* __restrict__ A, const u16* __restrict__ B, float* __restrict__ outF,
    const float* __restrict__ bv, const float* __restrict__ iLam, GemmArgs ga)
{
  __shared__ __align__(16) u16 As[64 * 32];
  __shared__ __align__(16) u16 Bs[128 * 32];
  if (blockIdx.x >= 256) {
    int q = blockIdx.x - 256;
    gemm64_body<3>(ga, q >> 3, q & 7, As, Bs);
    return;
  }
  const int bid = blockIdx.x;
  const int wg = (bid & 7) * 32 + (bid >> 3);
  const int bm = wg >> 1, bn = wg & 1;
  const int tid = threadIdx.x;
  const int l = tid & 63, w = tid >> 6;
  const size_t rowbA = 896 * 2, rowbB = 640 * 2;
  const char* Ab = (const char*)A + (size_t)bm * 64 * rowbA;
  const char* Bb = (const char*)B + (size_t)bn * 128 * rowbB;
  const int o = tid * 16, o2 = o + 4096;
  const int rA = o >> 6;
  const int csA = (((o >> 4) ^ rA) & 3) << 4;
  const int rB2 = o2 >> 6;
  const int csB2 = (((o2 >> 4) ^ rB2) & 3) << 4;
  char* AsB = (char*)As; char* BsB = (char*)Bs;
  const int wm = w >> 1, wn = w & 1;
  const int lr = l & 15, lk = l >> 4;
  const int slot = ((lk ^ lr) & 3) << 4;

  f32x4 acc[2][4];
  const f32x4 zz = {0.f, 0.f, 0.f, 0.f};
  #pragma unroll
  for (int i = 0; i < 2; i++)
    #pragma unroll
    for (int j = 0; j < 4; j++) acc[i][j] = zz;

  for (int k0 = 0; k0 < 640; k0 += 32) {
    gl16(Ab + (size_t)rA * rowbA + k0 * 2 + csA, AsB + o);
    gl16(Bb + (size_t)rA * rowbB + k0 * 2 + csA, BsB + o);
    gl16(Bb + (size_t)rB2 * rowbB + k0 * 2 + csB2, BsB + o2);
    __syncthreads();
    bf16x8 af[2], bfv[4];
    #pragma unroll
    for (int mi = 0; mi < 2; mi++)
      af[mi] = *(const bf16x8*)(AsB + (wm * 32 + mi * 16 + lr) * 64 + slot);
    #pragma unroll
    for (int ni = 0; ni < 4; ni++)
      bfv[ni] = *(const bf16x8*)(BsB + (wn * 64 + ni * 16 + lr) * 64 + slot);
    #pragma unroll
    for (int mi = 0; mi < 2; mi++)
      #pragma unroll
      for (int ni = 0; ni < 4; ni++)
        acc[mi][ni] = __builtin_amdgcn_mfma_f32_16x16x32_bf16(af[mi], bfv[ni], acc[mi][ni], 0, 0, 0);
    __syncthreads();
  }

  #pragma unroll
  for (int mi = 0; mi < 2; mi++) {
    #pragma unroll
    for (int ni = 0; ni < 4; ni++) {
      const int row0 = bm * 64 + wm * 32 + mi * 16 + lk * 4;
      const int col  = bn * 128 + wn * 64 + ni * 16 + lr;
      const float bvc = bv[col], il = iLam[col];
      #pragma unroll
      for (int r = 0; r < 4; r++)
        outF[(size_t)(row0 + r) * 256 + col] = (acc[mi][ni][r] + bvc) * il;
    }
  }
}

// ---------------------------------------------------------------------------
// 128x128-tile NT GEMM body, BK=32 single-buffer (R8-proven)
// PART 0: dx cols; PART 1: y cols (bn=0, B pre-offset to Qt y-rows)
// ---------------------------------------------------------------------------
template<int PART>
DEV void f2_body(const u16* A, const u16* B, float* dxOut, float* yOut,
                 int bm, int bn, char* sh)
{
  char* AsB = sh;            // 8 KB
  char* BsB = sh + 8192;     // 8 KB
  const int tid = threadIdx.x;
  const int l = tid & 63, w = tid >> 6;
  const size_t rowb = 896 * 2;
  const char* Ab = (const char*)A + (size_t)bm * 128 * rowb;
  const char* Bb = (const char*)B + (size_t)bn * 128 * rowb;
  const int o1 = tid * 16, o2 = o1 + 4096;
  const int r1 = o1 >> 6, r2 = o2 >> 6;
  const int c1 = (((o1 >> 4) ^ r1) & 3) << 4;
  const int c2 = (((o2 >> 4) ^ r2) & 3) << 4;
  const int wm = w >> 1, wn = w & 1;
  const int lr = l & 15, lk = l >> 4;
  const int slot = ((lk ^ lr) & 3) << 4;

  f32x4 acc[4][4];
  const f32x4 zz = {0.f, 0.f, 0.f, 0.f};
  #pragma unroll
  for (int i = 0; i < 4; i++)
    #pragma unroll
    for (int j = 0; j < 4; j++) acc[i][j] = zz;

  for (int k0 = 0; k0 < 896; k0 += 32) {
    gl16(Ab + (size_t)r1 * rowb + k0 * 2 + c1, AsB + o1);
    gl16(Ab + (size_t)r2 * rowb + k0 * 2 + c2, AsB + o2);
    gl16(Bb + (size_t)r1 * rowb + k0 * 2 + c1, BsB + o1);
    gl16(Bb + (size_t)r2 * rowb + k0 * 2 + c2, BsB + o2);
    __syncthreads();
    bf16x8 af[4], bfv[4];
    #pragma unroll
    for (int mi = 0; mi < 4; mi++)
      af[mi] = *(const bf16x8*)(AsB + (wm * 64 + mi * 16 + lr) * 64 + slot);
    #pragma unroll
    for (int ni = 0; ni < 4; ni++)
      bfv[ni] = *(const bf16x8*)(BsB + (wn * 64 + ni * 16 + lr) * 64 + slot);
    #pragma unroll
    for (int mi = 0; mi < 4; mi++)
      #pragma unroll
      for (int ni = 0; ni < 4; ni++)
        acc[mi][ni] = __builtin_amdgcn_mfma_f32_16x16x32_bf16(af[mi], bfv[ni], acc[mi][ni], 0, 0, 0);
    __syncthreads();
  }

  #pragma unroll
  for (int mi = 0; mi < 4; mi++) {
    #pragma unroll
    for (int ni = 0; ni < 4; ni++) {
      const int row0 = bm * 128 + wm * 64 + mi * 16 + lk * 4;
      const int col  = bn * 128 + wn * 64 + ni * 16 + lr;
      #pragma unroll
      for (int r = 0; r < 4; r++) {
        float v = acc[mi][ni][r];
        if (PART == 0) dxOut[(size_t)(row0 + r) * 512 + col] = v;
        else           yOut[(size_t)(row0 + r) * 128 + col] = v;
      }
    }
  }
}

// ---------------------------------------------------------------------------
// L4: blocks [0,64) = y-GEMM (128x128, XCD-swz); [64,176) = Qt (gemm64<2>)
// ---------------------------------------------------------------------------
__global__ __launch_bounds__(256) void k_l4(
    const u16* __restrict__ P, const u16* __restrict__ QtY,
    float* __restrict__ yOut, GemmArgs qt)
{
  __shared__ __align__(16) char sh[16384];
  if (blockIdx.x < 64) {
    const int bm = (blockIdx.x & 7) * 8 + (blockIdx.x >> 3);
    f2_body<1>(P, QtY, nullptr, yOut, bm, 0, sh);
    return;
  }
  int q = blockIdx.x - 64;                 // [0,112): bm in [0,8), bn in [0,14)
  gemm64_body<2>(qt, q / 14, q % 14, (u16*)sh, (u16*)(sh + 4096));
}

// ---------------------------------------------------------------------------
// L5: dx GEMM, 256 blocks (1/CU), XCD-swizzled
// ---------------------------------------------------------------------------
__global__ __launch_bounds__(256) void gemm_fdx(
    const u16* __restrict__ A, const u16* __restrict__ B, float* __restrict__ dxOut)
{
  __shared__ __align__(16) char sh[16384];
  const int bid = blockIdx.x;
  const int wg = (bid & 7) * 32 + (bid >> 3);
  f2_body<0>(A, B, dxOut, nullptr, wg >> 2, wg & 3, sh);
}

// ---------------------------------------------------------------------------
// L3 (128 thr): blocks [0,256) = tanh recurrence (32 rows each);
//               blocks [256,320) = Y1 = 2Y0 - Y0@T0 via gemm64h_body<4>
// ---------------------------------------------------------------------------
__global__ __launch_bounds__(128) void k_solve_a(
    const float* __restrict__ base2, const u16* __restrict__ Ddg2,
    const float* __restrict__ Dt16, u16* __restrict__ P, GemmArgs ga)
{
  __shared__ __align__(16) char DdL[2][16384];
  __shared__ __align__(16) float DtL[4096];
  __shared__ __align__(16) float tb[2][16][40];

  if (blockIdx.x >= 256) {
    int q = blockIdx.x - 256;
    gemm64h_body<4>(ga, q >> 3, q & 7, (u16*)&DdL[0][0], (u16*)&DdL[0][4096]);
    return;
  }

  const int tid = threadIdx.x, l = tid & 63, w = tid >> 6;
  const int r = l & 15, g = l >> 4;
  const int row = blockIdx.x * 32 + w * 16 + r;

  const char* DtG = (const char*)Dt16;
  #pragma unroll
  for (int i = 0; i < 8; i++)
    gl16(DtG + i * 2048 + tid * 16, (char*)DtL + i * 2048 + tid * 16);
  const char* DgG = (const char*)Ddg2;
  #pragma unroll
  for (int i = 0; i < 8; i++)
    gl16(DgG + i * 2048 + tid * 16, DdL[0] + i * 2048 + tid * 16);

  f32x4 st[16];
  const float* bp = base2 + (size_t)row * 256 + g * 4;
  #pragma unroll
  for (int t = 0; t < 16; t++) st[t] = *(const f32x4*)(bp + t * 16);

  u32x4 pkA[8];
  float* tbr = &tb[w][r][0];
  __syncthreads();

  #pragma unroll
  for (int sb = 0; sb < 8; sb++) {
    if (sb < 7) {
      #pragma unroll
      for (int i = 0; i < 8; i++)
        gl16(DgG + (sb + 1) * 16384 + i * 2048 + tid * 16,
             DdL[(sb + 1) & 1] + i * 2048 + tid * 16);
    }
    float ws[8];
    #pragma unroll
    for (int i = 0; i < 8; i++) ws[i] = 0.f;
    f32x4 vv[4];

    // ---- lo 16-tile
    *(f32x4*)(tbr + g * 4) = st[2 * sb];
    vv[0] = *(const f32x4*)(tbr);      vv[1] = *(const f32x4*)(tbr + 4);
    vv[2] = *(const f32x4*)(tbr + 8);  vv[3] = *(const f32x4*)(tbr + 12);
    {
      const float* dt = DtL + (2 * sb) * 256;
      #pragma unroll
      for (int k2 = 0; k2 < 16; k2++) {
        float v = vv[k2 >> 2][k2 & 3];
        float ex = __expf(2.f * v);
        float wv = 1.f - 2.f * __fdividef(1.f, ex + 1.f);
        if (g == (k2 >> 3)) ws[k2 & 7] = wv;
        #pragma unroll
        for (int j = k2 >> 2; j < 4; j++)
          vv[j] += wv * *(const f32x4*)(dt + k2 * 16 + j * 4);
      }
    }
    {
      u32x4 pk;
      pk.x = (u32)f2b(ws[0]) | ((u32)f2b(ws[1]) << 16);
      pk.y = (u32)f2b(ws[2]) | ((u32)f2b(ws[3]) << 16);
      pk.z = (u32)f2b(ws[4]) | ((u32)f2b(ws[5]) << 16);
      pk.w = (u32)f2b(ws[6]) | ((u32)f2b(ws[7]) << 16);
      union { u32x4 uu; bf16x8 bb; } cv; cv.uu = pk;
      bf16x8 Af = *(const bf16x8*)(DdL[sb & 1] + (2 * sb + 1) * 1024 + l * 16);
      st[2 * sb + 1] = __builtin_amdgcn_mfma_f32_16x16x32_bf16(Af, cv.bb, st[2 * sb + 1], 0, 0, 0);
    }
    // ---- hi 16-tile
    *(f32x4*)(tbr + g * 4) = st[2 * sb + 1];
    vv[0] = *(const f32x4*)(tbr);      vv[1] = *(const f32x4*)(tbr + 4);
    vv[2] = *(const f32x4*)(tbr + 8);  vv[3] = *(const f32x4*)(tbr + 12);
    {
      const float* dt = DtL + (2 * sb + 1) * 256;
      #pragma unroll
      for (int k2 = 0; k2 < 16; k2++) {
        float v = vv[k2 >> 2][k2 & 3];
        float ex = __expf(2.f * v);
        float wv = 1.f - 2.f * __fdividef(1.f, ex + 1.f);
        if (g == 2 + (k2 >> 3)) ws[k2 & 7] = wv;
        #pragma unroll
        for (int j = k2 >> 2; j < 4; j++)
          vv[j] += wv * *(const f32x4*)(dt + k2 * 16 + j * 4);
      }
    }
    {
      u32x4 pk;
      pk.x = (u32)f2b(ws[0]) | ((u32)f2b(ws[1]) << 16);
      pk.y = (u32)f2b(ws[2]) | ((u32)f2b(ws[3]) << 16);
      pk.z = (u32)f2b(ws[4]) | ((u32)f2b(ws[5]) << 16);
      pk.w = (u32)f2b(ws[6]) | ((u32)f2b(ws[7]) << 16);
      pkA[sb] = pk;
      union { u32x4 uu; bf16x8 bb; } cv; cv.uu = pk;
      #pragma unroll
      for (int t = 0; t < 16; t++) {
        if (t >= 2 * sb + 2) {
          bf16x8 Af = *(const bf16x8*)(DdL[sb & 1] + t * 1024 + l * 16);
          st[t] = __builtin_amdgcn_mfma_f32_16x16x32_bf16(Af, cv.bb, st[t], 0, 0, 0);
        }
      }
    }
    __syncthreads();
  }

  u16* Pr = P + (size_t)row * 896 + 640;
  #pragma unroll
  for (int sb = 0; sb < 8; sb++)
    *(u32x4*)(Pr + sb * 32 + g * 8) = pkA[sb];
}

// ---------------------------------------------------------------------------
extern "C" void kernel_launch(void* const* d_in, const int* in_sizes, int n_in,
                              void* d_out, int out_size, void* d_ws, size_t ws_size,
                              hipStream_t stream)
{
  const float* x   = (const float*)d_in[0];
  const float* u   = (const float*)d_in[1];
  const float* C1  = (const float*)d_in[2];
  const float* D11 = (const float*)d_in[3];
  const float* D12 = (const float*)d_in[4];
  const float* Lam = (const float*)d_in[5];
  const float* bv  = (const float*)d_in[6];
  const float* E   = (const float*)d_in[7];
  const float* F   = (const float*)d_in[8];
  const float* B1  = (const float*)d_in[9];
  const float* B2  = (const float*)d_in[10];
  const float* C2  = (const float*)d_in[11];
  const float* D21 = (const float*)d_in[12];

  char* ws = (char*)d_ws;
  u16*   P      = (u16*)(ws);                 // 14,680,064
  u16*   Qt     = (u16*)(ws + 14680064);      //  1,146,880
  u16*   Rt     = (u16*)(ws + 15826944);      //    327,680
  float* base2  = (float*)(ws + 16285696);    //  8,388,608
  u16*   Ddg2   = (u16*)(ws + 24674304);      //    131,072
  float* Dt16   = (float*)(ws + 24805376);    //     16,384
  u16*   Ebf    = (u16*)(ws + 24838144);      //    524,288
  u16*   Y0     = (u16*)(ws + 25362432);
  u16*   Z0     = (u16*)(ws + 25886720);
  u16*   T0T    = (u16*)(ws + 26411008);
  u16*   Y1     = (u16*)(ws + 26935296);
  u16*   McatT  = (u16*)(ws + 27459584);      //    917,504
  float* invLam = (float*)(ws + 28377088);

  float* dxOut = (float*)d_out;
  float* yOut  = dxOut + (size_t)8192 * 512;

  k_prepc<<<8209, 256, 0, stream>>>(x, u, C1, D11, D12, Lam, E, F, B1, B2, C2, D21,
                                    Ebf, Y0, Z0, McatT, Qt, Rt, invLam, Ddg2, Dt16, P);

  GemmArgs a{}; a.A = Ebf; a.B = Z0; a.K = 512; a.lda = 512; a.ldb = 512; a.outBT = T0T;
  gemm_b2<<<320, 256, 0, stream>>>(P, Rt, base2, bv, invLam, a);     // base2 + T0T

  GemmArgs b{}; b.A = Y0; b.B = T0T; b.K = 512; b.lda = 512; b.ldb = 512;
  b.outB = Y1; b.ldB = 512; b.Yprev = Y0;
  k_solve_a<<<320, 128, 0, stream>>>(base2, Ddg2, Dt16, P, b);       // w + Y1

  GemmArgs qq{}; qq.A = Y1; qq.B = McatT; qq.K = 512; qq.lda = 512; qq.ldb = 512;
  qq.outB = Qt; qq.ldB = 896;
  k_l4<<<176, 256, 0, stream>>>(P, Qt + (size_t)512 * 896, yOut, qq); // y + Qt

  gemm_fdx<<<256, 256, 0, stream>>>(P, Qt, dxOut);                   // dx
  (void)in_sizes; (void)n_in; (void)out_size; (void)ws_size;
}

// Round 11
// 79.313 us; speedup vs baseline: 1.1871x; 1.1871x over previous
//
#include <hip/hip_runtime.h>

typedef unsigned short u16;
typedef unsigned int   u32;
typedef __attribute__((ext_vector_type(8))) __bf16 bf16x8;
typedef __attribute__((ext_vector_type(4))) float  f32x4;
typedef __attribute__((ext_vector_type(4))) u16    u16x4;
typedef __attribute__((ext_vector_type(4))) u32    u32x4;

#define DEV __device__ __forceinline__

DEV u16 f2b(float f){ union{float f;u32 u;}a; a.f=f; u32 r=a.u + 0x7FFFu + ((a.u>>16)&1u); return (u16)(r>>16); }
DEV float b2f(u16 h){ union{u32 u;float f;}a; a.u=((u32)h)<<16; return a.f; }

typedef __attribute__((address_space(1))) void* gp1;
typedef __attribute__((address_space(3))) void* lp3;
DEV void gl16(const void* g, void* l){
  __builtin_amdgcn_global_load_lds((gp1)g, (lp3)l, 16, 0, 0);
}

struct GemmArgs {
  const u16* A; const u16* B; int K; int lda; int ldb;
  u16* outB; int ldB;
  u16* outBT;
  const u16* Yprev;
};

// ---------------------------------------------------------------------------
// L1 prep: transposes (blocks 0..703) + elementwise (rest)
// P: [x | u | w]; Rt: 256x640 = [C1 | D12]; Qt y-rows: [C2 | 0 | D21]
// ---------------------------------------------------------------------------
__global__ __launch_bounds__(256) void k_prepc(
    const float* __restrict__ x,  const float* __restrict__ u,
    const float* __restrict__ C1, const float* __restrict__ D11,
    const float* __restrict__ D12, const float* __restrict__ Lam,
    const float* __restrict__ E,  const float* __restrict__ F,
    const float* __restrict__ B1, const float* __restrict__ B2,
    const float* __restrict__ C2, const float* __restrict__ D21,
    u16* Ebf, u16* Y0, u16* Z0, u16* McatT, u16* Qt, u16* Rt,
    float* invLam, u16* Ddg2, float* Dt16, u16* P)
{
  if (blockIdx.x < 704) {                   // tiled transposes
    __shared__ float t[32][33];
    int bid = blockIdx.x;
    const int tx = threadIdx.x & 31, ty = threadIdx.x >> 5;
    const float* src; u16* dst; int srcC, nA, task;
    if (bid < 256)      { task = 0; src = E;   srcC = 512; dst = Z0;    nA = 16; }
    else if (bid < 512) { task = 1; src = F;   srcC = 512; dst = McatT; nA = 16; bid -= 256; }
    else if (bid < 640) { task = 2; src = B1;  srcC = 256; dst = McatT + (size_t)640 * 512; nA = 8;  bid -= 512; }
    else                { task = 3; src = B2;  srcC = 128; dst = McatT + (size_t)512 * 512; nA = 4;  bid -= 640; }
    const int a0 = (bid % nA) * 32;
    const int b0 = (bid / nA) * 32;
    #pragma unroll
    for (int k = 0; k < 4; k++) {
      int srow = b0 + ty + 8 * k;
      t[ty + 8 * k][tx] = src[(size_t)srow * srcC + a0 + tx];
    }
    __syncthreads();
    #pragma unroll
    for (int k = 0; k < 4; k++) {
      int drow = a0 + ty + 8 * k, dcol = b0 + tx;
      float v = t[tx][ty + 8 * k];
      if (task == 0) v = ((drow == dcol) ? 2.f : 0.f) - v;
      dst[(size_t)drow * 512 + dcol] = f2b(v);
    }
    return;
  }
  int idx = (blockIdx.x - 704) * 256 + threadIdx.x;
  if (idx < 262144) {                       // Ebf, Y0 = 2I-E
    int i = idx >> 9, j = idx & 511;
    float e = E[idx];
    Ebf[idx] = f2b(e);
    float dij = (i == j) ? 2.f : 0.f;
    Y0[idx] = f2b(dij - e);
    return;
  }
  idx -= 262144;
  if (idx < 114688) {                       // Qt rows 512..639 (y part)
    int j = idx / 896, k = idx - j * 896;
    float v = (k < 512) ? C2[j * 512 + k]
              : (k < 640 ? 0.f : D21[j * 256 + (k - 640)]);
    Qt[(size_t)(512 + j) * 896 + k] = f2b(v);
    return;
  }
  idx -= 114688;
  if (idx < 163840) {                       // Rt (256x640): [C1 | D12]
    int n = idx / 640, k = idx - n * 640;
    float v = (k < 512) ? C1[n * 512 + k] : D12[n * 128 + (k - 512)];
    Rt[idx] = f2b(v);
    return;
  }
  idx -= 163840;
  if (idx < 256) { invLam[idx] = 1.f / Lam[idx * 257]; return; }
  idx -= 256;
  if (idx < 65536) {                        // Ddg2 fragment layout
    int sb = idx >> 13, t = (idx >> 9) & 15, l = (idx >> 3) & 63, j = idx & 7;
    int r = l & 15, g = l >> 4;
    int n = t * 16 + r, k = sb * 32 + g * 8 + j;
    Ddg2[idx] = f2b(D11[n * 256 + k] * (1.f / Lam[n * 257]));
    return;
  }
  idx -= 65536;
  if (idx < 4096) {                         // Dt16 triangular diag blocks
    int T = idx >> 8, k2 = (idx >> 4) & 15, n2 = idx & 15;
    float v = 0.f;
    if (n2 > k2) {
      int n = T * 16 + n2;
      v = D11[n * 256 + T * 16 + k2] * (1.f / Lam[n * 257]);
    }
    Dt16[idx] = v;
    return;
  }
  idx -= 4096;
  {                                         // P = [x | u | .] bf16
    int b = idx / 160, t = idx - b * 160;
    f32x4 s; u16* dst;
    if (t < 128) { s = *(const f32x4*)(x + (size_t)b * 512 + t * 4); dst = P + (size_t)b * 896 + t * 4; }
    else         { s = *(const f32x4*)(u + (size_t)b * 128 + (t - 128) * 4); dst = P + (size_t)b * 896 + 512 + (t - 128) * 4; }
    u16x4 o; o.x = f2b(s.x); o.y = f2b(s.y); o.z = f2b(s.z); o.w = f2b(s.w);
    *(u16x4*)dst = o;
  }
}

// ---------------------------------------------------------------------------
// 64x64-tile NT GEMM body, 256 threads (2x2 waves of 32x32)
// ---------------------------------------------------------------------------
template<int EPI>
DEV void gemm64_body(const GemmArgs& g, int bm, int bn, u16* As, u16* Bs)
{
  const int tid = threadIdx.x;
  const int l = tid & 63, w = tid >> 6;
  const int K = g.K;
  const size_t rowbA = (size_t)g.lda * 2, rowbB = (size_t)g.ldb * 2;
  const char* Ab = (const char*)g.A + (size_t)bm * 64 * rowbA;
  const char* Bb = (const char*)g.B + (size_t)bn * 64 * rowbB;
  const int o = tid * 16;
  const int r0 = o >> 6;
  const int cs = (((o >> 4) ^ r0) & 3) << 4;
  char* AsB = (char*)As; char* BsB = (char*)Bs;
  const int wm = w >> 1, wn = w & 1;
  const int lr = l & 15, lk = l >> 4;
  const int slot = ((lk ^ lr) & 3) << 4;

  f32x4 acc[2][2];
  const f32x4 zz = {0.f, 0.f, 0.f, 0.f};
  acc[0][0] = zz; acc[0][1] = zz; acc[1][0] = zz; acc[1][1] = zz;

  for (int k0 = 0; k0 < K; k0 += 32) {
    gl16(Ab + (size_t)r0 * rowbA + k0 * 2 + cs, AsB + o);
    gl16(Bb + (size_t)r0 * rowbB + k0 * 2 + cs, BsB + o);
    __syncthreads();
    bf16x8 af[2], bfv[2];
    #pragma unroll
    for (int mi = 0; mi < 2; mi++)
      af[mi] = *(const bf16x8*)(AsB + (wm * 32 + mi * 16 + lr) * 64 + slot);
    #pragma unroll
    for (int ni = 0; ni < 2; ni++)
      bfv[ni] = *(const bf16x8*)(BsB + (wn * 32 + ni * 16 + lr) * 64 + slot);
    #pragma unroll
    for (int mi = 0; mi < 2; mi++)
      #pragma unroll
      for (int ni = 0; ni < 2; ni++)
        acc[mi][ni] = __builtin_amdgcn_mfma_f32_16x16x32_bf16(af[mi], bfv[ni], acc[mi][ni], 0, 0, 0);
    __syncthreads();
  }

  #pragma unroll
  for (int mi = 0; mi < 2; mi++) {
    #pragma unroll
    for (int ni = 0; ni < 2; ni++) {
      const int row0 = bm * 64 + wm * 32 + mi * 16 + lk * 4;
      const int col  = bn * 64 + wn * 32 + ni * 16 + lr;
      if (EPI == 2) {
        #pragma unroll
        for (int r = 0; r < 4; r++)
          g.outB[(size_t)(row0 + r) * g.ldB + col] = f2b(acc[mi][ni][r]);
      } else if (EPI == 3) {
        #pragma unroll
        for (int r = 0; r < 4; r++)
          g.outBT[(size_t)col * 512 + (row0 + r)] = f2b(acc[mi][ni][r]);
      }
    }
  }
}

template<int EPI>
__global__ __launch_bounds__(256) void gemm64(GemmArgs g)
{
  __shared__ __align__(16) u16 As[64 * 32];
  __shared__ __align__(16) u16 Bs[64 * 32];
  gemm64_body<EPI>(g, blockIdx.y, blockIdx.x, As, Bs);
}

// ---------------------------------------------------------------------------
// 64x64-tile NT GEMM body, 128 threads (2 waves of 32x64); EPI 4 = Y1
// ---------------------------------------------------------------------------
template<int EPI>
DEV void gemm64h_body(const GemmArgs& g, int bm, int bn, u16* As, u16* Bs)
{
  const int tid = threadIdx.x;
  const int l = tid & 63, w = tid >> 6;           // w in {0,1}
  const int K = g.K;
  const size_t rowbA = (size_t)g.lda * 2, rowbB = (size_t)g.ldb * 2;
  const char* Ab = (const char*)g.A + (size_t)bm * 64 * rowbA;
  const char* Bb = (const char*)g.B + (size_t)bn * 64 * rowbB;
  const int o1 = tid * 16, o2 = o1 + 2048;
  const int rA1 = o1 >> 6, rA2 = o2 >> 6;
  const int cs1 = (((o1 >> 4) ^ rA1) & 3) << 4;
  const int cs2 = (((o2 >> 4) ^ rA2) & 3) << 4;
  char* AsB = (char*)As; char* BsB = (char*)Bs;
  const int lr = l & 15, lk = l >> 4;
  const int slot = ((lk ^ lr) & 3) << 4;

  f32x4 acc[2][4];
  const f32x4 zz = {0.f, 0.f, 0.f, 0.f};
  #pragma unroll
  for (int i = 0; i < 2; i++)
    #pragma unroll
    for (int j = 0; j < 4; j++) acc[i][j] = zz;

  for (int k0 = 0; k0 < K; k0 += 32) {
    gl16(Ab + (size_t)rA1 * rowbA + k0 * 2 + cs1, AsB + o1);
    gl16(Ab + (size_t)rA2 * rowbA + k0 * 2 + cs2, AsB + o2);
    gl16(Bb + (size_t)rA1 * rowbB + k0 * 2 + cs1, BsB + o1);
    gl16(Bb + (size_t)rA2 * rowbB + k0 * 2 + cs2, BsB + o2);
    __syncthreads();
    bf16x8 af[2], bfv[4];
    #pragma unroll
    for (int mi = 0; mi < 2; mi++)
      af[mi] = *(const bf16x8*)(AsB + (w * 32 + mi * 16 + lr) * 64 + slot);
    #pragma unroll
    for (int ni = 0; ni < 4; ni++)
      bfv[ni] = *(const bf16x8*)(BsB + (ni * 16 + lr) * 64 + slot);
    #pragma unroll
    for (int mi = 0; mi < 2; mi++)
      #pragma unroll
      for (int ni = 0; ni < 4; ni++)
        acc[mi][ni] = __builtin_amdgcn_mfma_f32_16x16x32_bf16(af[mi], bfv[ni], acc[mi][ni], 0, 0, 0);
    __syncthreads();
  }

  #pragma unroll
  for (int mi = 0; mi < 2; mi++) {
    #pragma unroll
    for (int ni = 0; ni < 4; ni++) {
      const int row0 = bm * 64 + w * 32 + mi * 16 + lk * 4;
      const int col  = bn * 64 + ni * 16 + lr;
      if (EPI == 4) {
        #pragma unroll
        for (int r = 0; r < 4; r++) {
          int row = row0 + r;
          float d = 2.f * b2f(g.Yprev[row * 512 + col]) - acc[mi][ni][r];
          g.outB[(size_t)row * 512 + col] = f2b(d);
        }
      }
    }
  }
}

// ---------------------------------------------------------------------------
// L2: blocks [0,256) = base2 GEMM (64x128, K=640, XCD-swizzled);
//     blocks [256,320) = T0T = (E@Y0)^T via gemm64_body<3>
// ---------------------------------------------------------------------------
__global__ __launch_bounds__(256) void gemm_b2(
    const u16* __restrict__ A, const u16* __restrict__ B, float* __restrict__ outF,
    const float* __restrict__ bv, const float* __restrict__ iLam, GemmArgs ga)
{
  __shared__ __align__(16) u16 As[64 * 32];
  __shared__ __align__(16) u16 Bs[128 * 32];
  if (blockIdx.x >= 256) {
    int q = blockIdx.x - 256;
    gemm64_body<3>(ga, q >> 3, q & 7, As, Bs);
    return;
  }
  const int bid = blockIdx.x;
  const int wg = (bid & 7) * 32 + (bid >> 3);
  const int bm = wg >> 1, bn = wg & 1;
  const int tid = threadIdx.x;
  const int l = tid & 63, w = tid >> 6;
  const size_t rowbA = 896 * 2, rowbB = 640 * 2;
  const char* Ab = (const char*)A + (size_t)bm * 64 * rowbA;
  const char* Bb = (const char*)B + (size_t)bn * 128 * rowbB;
  const int o = tid * 16, o2 = o + 4096;
  const int rA = o >> 6;
  const int csA = (((o >> 4) ^ rA) & 3) << 4;
  const int rB2 = o2 >> 6;
  const int csB2 = (((o2 >> 4) ^ rB2) & 3) << 4;
  char* AsB = (char*)As; char* BsB = (char*)Bs;
  const int wm = w >> 1, wn = w & 1;
  const int lr = l & 15, lk = l >> 4;
  const int slot = ((lk ^ lr) & 3) << 4;

  f32x4 acc[2][4];
  const f32x4 zz = {0.f, 0.f, 0.f, 0.f};
  #pragma unroll
  for (int i = 0; i < 2; i++)
    #pragma unroll
    for (int j = 0; j < 4; j++) acc[i][j] = zz;

  for (int k0 = 0; k0 < 640; k0 += 32) {
    gl16(Ab + (size_t)rA * rowbA + k0 * 2 + csA, AsB + o);
    gl16(Bb + (size_t)rA * rowbB + k0 * 2 + csA, BsB + o);
    gl16(Bb + (size_t)rB2 * rowbB + k0 * 2 + csB2, BsB + o2);
    __syncthreads();
    bf16x8 af[2], bfv[4];
    #pragma unroll
    for (int mi = 0; mi < 2; mi++)
      af[mi] = *(const bf16x8*)(AsB + (wm * 32 + mi * 16 + lr) * 64 + slot);
    #pragma unroll
    for (int ni = 0; ni < 4; ni++)
      bfv[ni] = *(const bf16x8*)(BsB + (wn * 64 + ni * 16 + lr) * 64 + slot);
    #pragma unroll
    for (int mi = 0; mi < 2; mi++)
      #pragma unroll
      for (int ni = 0; ni < 4; ni++)
        acc[mi][ni] = __builtin_amdgcn_mfma_f32_16x16x32_bf16(af[mi], bfv[ni], acc[mi][ni], 0, 0, 0);
    __syncthreads();
  }

  #pragma unroll
  for (int mi = 0; mi < 2; mi++) {
    #pragma unroll
    for (int ni = 0; ni < 4; ni++) {
      const int row0 = bm * 64 + wm * 32 + mi * 16 + lk * 4;
      const int col  = bn * 128 + wn * 64 + ni * 16 + lr;
      const float bvc = bv[col], il = iLam[col];
      #pragma unroll
      for (int r = 0; r < 4; r++)
        outF[(size_t)(row0 + r) * 256 + col] = (acc[mi][ni][r] + bvc) * il;
    }
  }
}

// ---------------------------------------------------------------------------
// L5 final GEMM: 128x64 tile, K=896; grid 640 XCD-swizzled (2.5 blocks/CU)
// dx (cols<512) / y split by col
// ---------------------------------------------------------------------------
__global__ __launch_bounds__(256) void gemm_f(
    const u16* __restrict__ A, const u16* __restrict__ B,
    float* __restrict__ dxOut, float* __restrict__ yOut)
{
  __shared__ __align__(16) u16 As[128 * 32];
  __shared__ __align__(16) u16 Bs[64 * 32];
  const int bid = blockIdx.x;
  const int wg = (bid & 7) * 80 + (bid >> 3);
  const int bm = wg / 10, bn = wg - bm * 10;
  const int tid = threadIdx.x;
  const int l = tid & 63, w = tid >> 6;
  const size_t rowb = 896 * 2;
  const char* Ab = (const char*)A + (size_t)bm * 128 * rowb;
  const char* Bb = (const char*)B + (size_t)bn * 64 * rowb;
  const int o = tid * 16, o2 = o + 4096;
  const int r1 = o >> 6, r2 = o2 >> 6;
  const int c1 = (((o >> 4) ^ r1) & 3) << 4;
  const int c2 = (((o2 >> 4) ^ r2) & 3) << 4;
  char* AsB = (char*)As; char* BsB = (char*)Bs;
  const int wm = w >> 1, wn = w & 1;
  const int lr = l & 15, lk = l >> 4;
  const int slot = ((lk ^ lr) & 3) << 4;

  f32x4 acc[4][2];
  const f32x4 zz = {0.f, 0.f, 0.f, 0.f};
  #pragma unroll
  for (int i = 0; i < 4; i++)
    #pragma unroll
    for (int j = 0; j < 2; j++) acc[i][j] = zz;

  for (int k0 = 0; k0 < 896; k0 += 32) {
    gl16(Ab + (size_t)r1 * rowb + k0 * 2 + c1, AsB + o);
    gl16(Ab + (size_t)r2 * rowb + k0 * 2 + c2, AsB + o2);
    gl16(Bb + (size_t)r1 * rowb + k0 * 2 + c1, BsB + o);
    __syncthreads();
    bf16x8 af[4], bfv[2];
    #pragma unroll
    for (int mi = 0; mi < 4; mi++)
      af[mi] = *(const bf16x8*)(AsB + (wm * 64 + mi * 16 + lr) * 64 + slot);
    #pragma unroll
    for (int ni = 0; ni < 2; ni++)
      bfv[ni] = *(const bf16x8*)(BsB + (wn * 32 + ni * 16 + lr) * 64 + slot);
    #pragma unroll
    for (int mi = 0; mi < 4; mi++)
      #pragma unroll
      for (int ni = 0; ni < 2; ni++)
        acc[mi][ni] = __builtin_amdgcn_mfma_f32_16x16x32_bf16(af[mi], bfv[ni], acc[mi][ni], 0, 0, 0);
    __syncthreads();
  }

  #pragma unroll
  for (int mi = 0; mi < 4; mi++) {
    #pragma unroll
    for (int ni = 0; ni < 2; ni++) {
      const int row0 = bm * 128 + wm * 64 + mi * 16 + lk * 4;
      const int col  = bn * 64 + wn * 32 + ni * 16 + lr;
      #pragma unroll
      for (int r = 0; r < 4; r++) {
        float v = acc[mi][ni][r];
        if (col < 512) dxOut[(size_t)(row0 + r) * 512 + col] = v;
        else           yOut[(size_t)(row0 + r) * 128 + (col - 512)] = v;
      }
    }
  }
}

// ---------------------------------------------------------------------------
// L3 (128 thr): blocks [0,256) = tanh recurrence (32 rows each);
//               blocks [256,320) = Y1 = 2Y0 - Y0@T0 via gemm64h_body<4>
// ---------------------------------------------------------------------------
__global__ __launch_bounds__(128) void k_solve_a(
    const float* __restrict__ base2, const u16* __restrict__ Ddg2,
    const float* __restrict__ Dt16, u16* __restrict__ P, GemmArgs ga)
{
  __shared__ __align__(16) char DdL[2][16384];
  __shared__ __align__(16) float DtL[4096];
  __shared__ __align__(16) float tb[2][16][40];

  if (blockIdx.x >= 256) {
    int q = blockIdx.x - 256;
    gemm64h_body<4>(ga, q >> 3, q & 7, (u16*)&DdL[0][0], (u16*)&DdL[0][4096]);
    return;
  }

  const int tid = threadIdx.x, l = tid & 63, w = tid >> 6;
  const int r = l & 15, g = l >> 4;
  const int row = blockIdx.x * 32 + w * 16 + r;

  const char* DtG = (const char*)Dt16;
  #pragma unroll
  for (int i = 0; i < 8; i++)
    gl16(DtG + i * 2048 + tid * 16, (char*)DtL + i * 2048 + tid * 16);
  const char* DgG = (const char*)Ddg2;
  #pragma unroll
  for (int i = 0; i < 8; i++)
    gl16(DgG + i * 2048 + tid * 16, DdL[0] + i * 2048 + tid * 16);

  f32x4 st[16];
  const float* bp = base2 + (size_t)row * 256 + g * 4;
  #pragma unroll
  for (int t = 0; t < 16; t++) st[t] = *(const f32x4*)(bp + t * 16);

  u32x4 pkA[8];
  float* tbr = &tb[w][r][0];
  __syncthreads();

  #pragma unroll
  for (int sb = 0; sb < 8; sb++) {
    if (sb < 7) {
      #pragma unroll
      for (int i = 0; i < 8; i++)
        gl16(DgG + (sb + 1) * 16384 + i * 2048 + tid * 16,
             DdL[(sb + 1) & 1] + i * 2048 + tid * 16);
    }
    float ws[8];
    #pragma unroll
    for (int i = 0; i < 8; i++) ws[i] = 0.f;
    f32x4 vv[4];

    // ---- lo 16-tile
    *(f32x4*)(tbr + g * 4) = st[2 * sb];
    vv[0] = *(const f32x4*)(tbr);      vv[1] = *(const f32x4*)(tbr + 4);
    vv[2] = *(const f32x4*)(tbr + 8);  vv[3] = *(const f32x4*)(tbr + 12);
    {
      const float* dt = DtL + (2 * sb) * 256;
      #pragma unroll
      for (int k2 = 0; k2 < 16; k2++) {
        float v = vv[k2 >> 2][k2 & 3];
        float ex = __expf(2.f * v);
        float wv = 1.f - 2.f * __fdividef(1.f, ex + 1.f);
        if (g == (k2 >> 3)) ws[k2 & 7] = wv;
        #pragma unroll
        for (int j = k2 >> 2; j < 4; j++)
          vv[j] += wv * *(const f32x4*)(dt + k2 * 16 + j * 4);
      }
    }
    {
      u32x4 pk;
      pk.x = (u32)f2b(ws[0]) | ((u32)f2b(ws[1]) << 16);
      pk.y = (u32)f2b(ws[2]) | ((u32)f2b(ws[3]) << 16);
      pk.z = (u32)f2b(ws[4]) | ((u32)f2b(ws[5]) << 16);
      pk.w = (u32)f2b(ws[6]) | ((u32)f2b(ws[7]) << 16);
      union { u32x4 uu; bf16x8 bb; } cv; cv.uu = pk;
      bf16x8 Af = *(const bf16x8*)(DdL[sb & 1] + (2 * sb + 1) * 1024 + l * 16);
      st[2 * sb + 1] = __builtin_amdgcn_mfma_f32_16x16x32_bf16(Af, cv.bb, st[2 * sb + 1], 0, 0, 0);
    }
    // ---- hi 16-tile
    *(f32x4*)(tbr + g * 4) = st[2 * sb + 1];
    vv[0] = *(const f32x4*)(tbr);      vv[1] = *(const f32x4*)(tbr + 4);
    vv[2] = *(const f32x4*)(tbr + 8);  vv[3] = *(const f32x4*)(tbr + 12);
    {
      const float* dt = DtL + (2 * sb + 1) * 256;
      #pragma unroll
      for (int k2 = 0; k2 < 16; k2++) {
        float v = vv[k2 >> 2][k2 & 3];
        float ex = __expf(2.f * v);
        float wv = 1.f - 2.f * __fdividef(1.f, ex + 1.f);
        if (g == 2 + (k2 >> 3)) ws[k2 & 7] = wv;
        #pragma unroll
        for (int j = k2 >> 2; j < 4; j++)
          vv[j] += wv * *(const f32x4*)(dt + k2 * 16 + j * 4);
      }
    }
    {
      u32x4 pk;
      pk.x = (u32)f2b(ws[0]) | ((u32)f2b(ws[1]) << 16);
      pk.y = (u32)f2b(ws[2]) | ((u32)f2b(ws[3]) << 16);
      pk.z = (u32)f2b(ws[4]) | ((u32)f2b(ws[5]) << 16);
      pk.w = (u32)f2b(ws[6]) | ((u32)f2b(ws[7]) << 16);
      pkA[sb] = pk;
      union { u32x4 uu; bf16x8 bb; } cv; cv.uu = pk;
      #pragma unroll
      for (int t = 0; t < 16; t++) {
        if (t >= 2 * sb + 2) {
          bf16x8 Af = *(const bf16x8*)(DdL[sb & 1] + t * 1024 + l * 16);
          st[t] = __builtin_amdgcn_mfma_f32_16x16x32_bf16(Af, cv.bb, st[t], 0, 0, 0);
        }
      }
    }
    __syncthreads();
  }

  u16* Pr = P + (size_t)row * 896 + 640;
  #pragma unroll
  for (int sb = 0; sb < 8; sb++)
    *(u32x4*)(Pr + sb * 32 + g * 8) = pkA[sb];
}

// ---------------------------------------------------------------------------
extern "C" void kernel_launch(void* const* d_in, const int* in_sizes, int n_in,
                              void* d_out, int out_size, void* d_ws, size_t ws_size,
                              hipStream_t stream)
{
  const float* x   = (const float*)d_in[0];
  const float* u   = (const float*)d_in[1];
  const float* C1  = (const float*)d_in[2];
  const float* D11 = (const float*)d_in[3];
  const float* D12 = (const float*)d_in[4];
  const float* Lam = (const float*)d_in[5];
  const float* bv  = (const float*)d_in[6];
  const float* E   = (const float*)d_in[7];
  const float* F   = (const float*)d_in[8];
  const float* B1  = (const float*)d_in[9];
  const float* B2  = (const float*)d_in[10];
  const float* C2  = (const float*)d_in[11];
  const float* D21 = (const float*)d_in[12];

  char* ws = (char*)d_ws;
  u16*   P      = (u16*)(ws);                 // 14,680,064
  u16*   Qt     = (u16*)(ws + 14680064);      //  1,146,880
  u16*   Rt     = (u16*)(ws + 15826944);      //    327,680
  float* base2  = (float*)(ws + 16285696);    //  8,388,608
  u16*   Ddg2   = (u16*)(ws + 24674304);      //    131,072
  float* Dt16   = (float*)(ws + 24805376);    //     16,384
  u16*   Ebf    = (u16*)(ws + 24838144);      //    524,288
  u16*   Y0     = (u16*)(ws + 25362432);
  u16*   Z0     = (u16*)(ws + 25886720);
  u16*   T0T    = (u16*)(ws + 26411008);
  u16*   Y1     = (u16*)(ws + 26935296);
  u16*   McatT  = (u16*)(ws + 27459584);      //    917,504
  float* invLam = (float*)(ws + 28377088);

  float* dxOut = (float*)d_out;
  float* yOut  = dxOut + (size_t)8192 * 512;

  k_prepc<<<8209, 256, 0, stream>>>(x, u, C1, D11, D12, Lam, E, F, B1, B2, C2, D21,
                                    Ebf, Y0, Z0, McatT, Qt, Rt, invLam, Ddg2, Dt16, P);

  GemmArgs a{}; a.A = Ebf; a.B = Z0; a.K = 512; a.lda = 512; a.ldb = 512; a.outBT = T0T;
  gemm_b2<<<320, 256, 0, stream>>>(P, Rt, base2, bv, invLam, a);     // base2 + T0T

  GemmArgs b{}; b.A = Y0; b.B = T0T; b.K = 512; b.lda = 512; b.ldb = 512;
  b.outB = Y1; b.ldB = 512; b.Yprev = Y0;
  k_solve_a<<<320, 128, 0, stream>>>(base2, Ddg2, Dt16, P, b);       // w + Y1

  GemmArgs qq{}; qq.A = Y1; qq.B = McatT; qq.K = 512; qq.lda = 512; qq.ldb = 512;
  qq.outB = Qt; qq.ldB = 896;
  gemm64<2><<<dim3(14, 8), 256, 0, stream>>>(qq);                    // Qt[0:512]

  gemm_f<<<640, 256, 0, stream>>>(P, Qt, dxOut, yOut);               // [dx | y]
  (void)in_sizes; (void)n_in; (void)out_size; (void)ws_size;
}